// Round 1
// baseline (5881.020 us; speedup 1.0000x reference)
//
#include <hip/hip_runtime.h>
#include <math.h>

#define NN 100000
#define NE 500000
#define NREL 3
#define F 128

__device__ __forceinline__ float sigm(float x) { return 1.f / (1.f + __expf(-x)); }

// ---- degree counting (int atomics into ws, reinterpreted) ----
__global__ void count_deg(const int* __restrict__ src, const int* __restrict__ dst,
                          int* __restrict__ cnt_out, int* __restrict__ cnt_in) {
  int i = blockIdx.x * blockDim.x + threadIdx.x;
  if (i >= NREL * NE) return;
  int r = i / NE;
  atomicAdd(&cnt_out[r * NN + src[i]], 1);
  atomicAdd(&cnt_in[r * NN + dst[i]], 1);
}

// in-place: int count bits -> float rsqrt(max(c,1)) (and /3 for in-degree)
__global__ void make_rs(float* __restrict__ rs_out, float* __restrict__ rs_in3) {
  int i = blockIdx.x * blockDim.x + threadIdx.x;
  if (i >= NREL * NN) return;
  int c0 = __float_as_int(rs_out[i]);
  rs_out[i] = rsqrtf((float)(c0 < 1 ? 1 : c0));
  int c1 = __float_as_int(rs_in3[i]);
  rs_in3[i] = rsqrtf((float)(c1 < 1 ? 1 : c1)) * (1.f / 3.f);
}

// h[n][:] = mean_r b[r][:]
__global__ void init_bias(float4* __restrict__ h4, const float4* __restrict__ b4) {
  int i = blockIdx.x * blockDim.x + threadIdx.x;
  if (i >= NN * (F / 4)) return;
  int q = i & 31;
  float4 a = b4[q], b = b4[32 + q], c = b4[64 + q];
  float4 v;
  v.x = (a.x + b.x + c.x) * (1.f / 3.f);
  v.y = (a.y + b.y + c.y) * (1.f / 3.f);
  v.z = (a.z + b.z + c.z) * (1.f / 3.f);
  v.w = (a.w + b.w + c.w) * (1.f / 3.f);
  h4[i] = v;
}

// Y = rowscale(opt-ReLU(A)) @ W ;  A:[NN,128] W:[128,128]
// 256 threads, block tile 128x128, thread tile 8x8, K-tiles of 32.
template <bool RELU>
__global__ __launch_bounds__(256, 4)
void gemm_rowscale(const float* __restrict__ A, const float* __restrict__ rs,
                   const float* __restrict__ W, float* __restrict__ Y) {
  __shared__ float As[128][34];   // pad 34: 8-row stride = 272 floats -> 2-way max
  __shared__ float Ws[32][132];   // pad 132: float4-aligned rows, 2-way max
  const int row0 = blockIdx.x * 128;
  const int tid = (int)threadIdx.x;
  const int rg = tid >> 4;   // 0..15 -> rows rg*8+i
  const int cg = tid & 15;   // cols cg*4 .. +3 and 64+cg*4 .. +3
  float acc[8][8] = {};

  for (int kt = 0; kt < 4; ++kt) {
    __syncthreads();
    // stage A tile 128x32 (scaled, optional relu)
#pragma unroll
    for (int it = 0; it < 4; ++it) {
      int lin = (it * 256 + tid) << 2;   // 0..4095
      int r = lin >> 5, c = lin & 31;
      int gr = row0 + r;
      float4 v = make_float4(0.f, 0.f, 0.f, 0.f);
      if (gr < NN) {
        v = *(const float4*)(A + (size_t)gr * F + kt * 32 + c);
        float s = rs[gr];
        if (RELU) {
          v.x = fmaxf(v.x, 0.f) * s; v.y = fmaxf(v.y, 0.f) * s;
          v.z = fmaxf(v.z, 0.f) * s; v.w = fmaxf(v.w, 0.f) * s;
        } else {
          v.x *= s; v.y *= s; v.z *= s; v.w *= s;
        }
      }
      As[r][c] = v.x; As[r][c + 1] = v.y; As[r][c + 2] = v.z; As[r][c + 3] = v.w;
    }
    // stage W tile 32x128
#pragma unroll
    for (int it = 0; it < 4; ++it) {
      int lin = (it * 256 + tid) << 2;   // 0..4095
      int kk = lin >> 7, j = lin & 127;
      float4 wv = *(const float4*)(W + (size_t)(kt * 32 + kk) * F + j);
      *(float4*)&Ws[kk][j] = wv;
    }
    __syncthreads();
#pragma unroll
    for (int kk = 0; kk < 32; ++kk) {
      float a[8];
#pragma unroll
      for (int i = 0; i < 8; ++i) a[i] = As[rg * 8 + i][kk];
      const float4 w0 = *(const float4*)&Ws[kk][cg * 4];
      const float4 w1 = *(const float4*)&Ws[kk][64 + cg * 4];
#pragma unroll
      for (int i = 0; i < 8; ++i) {
        acc[i][0] = fmaf(a[i], w0.x, acc[i][0]);
        acc[i][1] = fmaf(a[i], w0.y, acc[i][1]);
        acc[i][2] = fmaf(a[i], w0.z, acc[i][2]);
        acc[i][3] = fmaf(a[i], w0.w, acc[i][3]);
        acc[i][4] = fmaf(a[i], w1.x, acc[i][4]);
        acc[i][5] = fmaf(a[i], w1.y, acc[i][5]);
        acc[i][6] = fmaf(a[i], w1.z, acc[i][6]);
        acc[i][7] = fmaf(a[i], w1.w, acc[i][7]);
      }
    }
  }
#pragma unroll
  for (int i = 0; i < 8; ++i) {
    int gr = row0 + rg * 8 + i;
    if (gr < NN) {
      float4 o0 = make_float4(acc[i][0], acc[i][1], acc[i][2], acc[i][3]);
      float4 o1 = make_float4(acc[i][4], acc[i][5], acc[i][6], acc[i][7]);
      *(float4*)(Y + (size_t)gr * F + cg * 4) = o0;
      *(float4*)(Y + (size_t)gr * F + 64 + cg * 4) = o1;
    }
  }
}

// h[dst] += y[src] * rs_in3[dst]   (f32 atomics, 4 per thread)
__global__ void scatter_add(const float4* __restrict__ Y4, const int* __restrict__ src,
                            const int* __restrict__ dst, const float* __restrict__ rs_in3,
                            float* __restrict__ H) {
  const int total = NE * (F / 4);   // 16M
  int stride = gridDim.x * blockDim.x;
  for (int idx = blockIdx.x * blockDim.x + threadIdx.x; idx < total; idx += stride) {
    int e = idx >> 5, q = idx & 31;
    int s = src[e], d = dst[e];
    float sc = rs_in3[d];
    float4 v = Y4[(size_t)s * 32 + q];
    float* hp = H + (size_t)d * F + q * 4;
    atomicAdd(hp + 0, v.x * sc);
    atomicAdd(hp + 1, v.y * sc);
    atomicAdd(hp + 2, v.z * sc);
    atomicAdd(hp + 3, v.w * sc);
  }
}

// Fused BiLSTM single step: out[n][0:64]=f-dir, [64:128]=b-dir. Only gates i,g,o.
// 512 threads, 64 rows/block, gate-col space m = g*128 + j (j=output col, g in {i,g,o}).
__global__ __launch_bounds__(512, 4)
void lstm_fused(const float* __restrict__ H,
                const float* __restrict__ Wf, const float* __restrict__ bif,
                const float* __restrict__ bhf,
                const float* __restrict__ Wb, const float* __restrict__ bib,
                const float* __restrict__ bhb,
                float* __restrict__ out) {
  __shared__ float As[64][34];
  __shared__ float Ws[32][392];   // [k][m], m in [0,384)
  __shared__ float bsel[384];
  const int row0 = blockIdx.x * 64;
  const int tid = (int)threadIdx.x;
  const int rg = tid >> 5;  // 0..15 -> rows rg*4+i
  const int cg = tid & 31;  // out cols cg*4+t

  if (tid < 384) {
    int g = tid >> 7, j = tid & 127;
    int dir = j >> 6, jj = j & 63;
    int grow = (g == 0) ? jj : (g == 1) ? (128 + jj) : (192 + jj);
    bsel[tid] = dir ? (bib[grow] + bhb[grow]) : (bif[grow] + bhf[grow]);
  }

  float acc[3][4][4] = {};
  for (int kt = 0; kt < 4; ++kt) {
    __syncthreads();
    // stage A: 64x32
    {
      int lin = tid << 2;             // 0..2047
      int r = lin >> 5, c = lin & 31;
      int gr = row0 + r;
      float4 v = make_float4(0.f, 0.f, 0.f, 0.f);
      if (gr < NN) v = *(const float4*)(H + (size_t)gr * F + kt * 32 + c);
      As[r][c] = v.x; As[r][c + 1] = v.y; As[r][c + 2] = v.z; As[r][c + 3] = v.w;
    }
    // stage Ws: 32 x 384, gathered by gate-row, contiguous along k
#pragma unroll
    for (int it = 0; it < 6; ++it) {
      int lin = it * 512 + tid;       // 0..3071 = 384 m * 8 kq
      int m = lin % 384;
      int kq = lin / 384;             // 0..7
      int g = m >> 7, j = m & 127, dir = j >> 6, jj = j & 63;
      int grow = (g == 0) ? jj : (g == 1) ? (128 + jj) : (192 + jj);
      const float* Wd = dir ? Wb : Wf;
      float4 wv = *(const float4*)(Wd + (size_t)grow * F + kt * 32 + kq * 4);
      Ws[kq * 4 + 0][m] = wv.x;
      Ws[kq * 4 + 1][m] = wv.y;
      Ws[kq * 4 + 2][m] = wv.z;
      Ws[kq * 4 + 3][m] = wv.w;
    }
    __syncthreads();
#pragma unroll
    for (int kk = 0; kk < 32; ++kk) {
      float a[4];
#pragma unroll
      for (int i = 0; i < 4; ++i) a[i] = As[rg * 4 + i][kk];
      const float4 w0 = *(const float4*)&Ws[kk][cg * 4];
      const float4 w1 = *(const float4*)&Ws[kk][128 + cg * 4];
      const float4 w2 = *(const float4*)&Ws[kk][256 + cg * 4];
#pragma unroll
      for (int i = 0; i < 4; ++i) {
        acc[0][i][0] = fmaf(a[i], w0.x, acc[0][i][0]);
        acc[0][i][1] = fmaf(a[i], w0.y, acc[0][i][1]);
        acc[0][i][2] = fmaf(a[i], w0.z, acc[0][i][2]);
        acc[0][i][3] = fmaf(a[i], w0.w, acc[0][i][3]);
        acc[1][i][0] = fmaf(a[i], w1.x, acc[1][i][0]);
        acc[1][i][1] = fmaf(a[i], w1.y, acc[1][i][1]);
        acc[1][i][2] = fmaf(a[i], w1.z, acc[1][i][2]);
        acc[1][i][3] = fmaf(a[i], w1.w, acc[1][i][3]);
        acc[2][i][0] = fmaf(a[i], w2.x, acc[2][i][0]);
        acc[2][i][1] = fmaf(a[i], w2.y, acc[2][i][1]);
        acc[2][i][2] = fmaf(a[i], w2.z, acc[2][i][2]);
        acc[2][i][3] = fmaf(a[i], w2.w, acc[2][i][3]);
      }
    }
  }
#pragma unroll
  for (int i = 0; i < 4; ++i) {
    int gr = row0 + rg * 4 + i;
    if (gr < NN) {
      float4 o;
#pragma unroll
      for (int t = 0; t < 4; ++t) {
        int j = cg * 4 + t;
        float iv = acc[0][i][t] + bsel[j];
        float gv = acc[1][i][t] + bsel[128 + j];
        float ov = acc[2][i][t] + bsel[256 + j];
        float c = sigm(iv) * tanhf(gv);
        float oo = sigm(ov) * tanhf(c);
        (&o.x)[t] = oo;
      }
      *(float4*)(out + (size_t)gr * F + cg * 4) = o;
    }
  }
}

extern "C" void kernel_launch(void* const* d_in, const int* in_sizes, int n_in,
                              void* d_out, int out_size, void* d_ws, size_t ws_size,
                              hipStream_t stream) {
  const float* x = (const float*)d_in[0];
  const int* src = (const int*)d_in[1];
  const int* dst = (const int*)d_in[2];
  const float* W1 = (const float*)d_in[3];
  const float* b1 = (const float*)d_in[4];
  const float* W2 = (const float*)d_in[5];
  const float* b2 = (const float*)d_in[6];
  const float* Wih_f = (const float*)d_in[7];
  const float* bih_f = (const float*)d_in[9];
  const float* bhh_f = (const float*)d_in[10];
  const float* Wih_b = (const float*)d_in[11];
  const float* bih_b = (const float*)d_in[13];
  const float* bhh_b = (const float*)d_in[14];
  float* out = (float*)d_out;

  float* rs_out = (float*)d_ws;                   // 3*NN
  float* rs_in3 = rs_out + 3 * NN;                // 3*NN
  float* y = rs_in3 + 3 * NN;                     // NN*F
  float* h1 = y + (size_t)NN * F;                 // NN*F

  // degrees -> rsqrt normalizers
  hipMemsetAsync(rs_out, 0, (size_t)6 * NN * sizeof(float), stream);
  count_deg<<<(NREL * NE + 255) / 256, 256, 0, stream>>>(src, dst, (int*)rs_out, (int*)rs_in3);
  make_rs<<<(NREL * NN + 255) / 256, 256, 0, stream>>>(rs_out, rs_in3);

  // layer 1: h1 = relu applied at consumption; h1 holds pre-relu mean
  init_bias<<<(NN * 32 + 255) / 256, 256, 0, stream>>>((float4*)h1, (const float4*)b1);
  for (int r = 0; r < NREL; ++r) {
    gemm_rowscale<false><<<(NN + 127) / 128, 256, 0, stream>>>(x, rs_out + r * NN, W1 + (size_t)r * F * F, y);
    scatter_add<<<8192, 256, 0, stream>>>((const float4*)y, src + r * NE, dst + r * NE, rs_in3 + r * NN, h1);
  }

  // layer 2: accumulate into d_out (h2)
  init_bias<<<(NN * 32 + 255) / 256, 256, 0, stream>>>((float4*)out, (const float4*)b2);
  for (int r = 0; r < NREL; ++r) {
    gemm_rowscale<true><<<(NN + 127) / 128, 256, 0, stream>>>(h1, rs_out + r * NN, W2 + (size_t)r * F * F, y);
    scatter_add<<<8192, 256, 0, stream>>>((const float4*)y, src + r * NE, dst + r * NE, rs_in3 + r * NN, out);
  }

  // fused BiLSTM step, in place on d_out
  lstm_fused<<<(NN + 63) / 64, 512, 0, stream>>>(out, Wih_f, bih_f, bhh_f,
                                                 Wih_b, bih_b, bhh_b, out);
}

// Round 2
// 1218.068 us; speedup vs baseline: 4.8282x; 4.8282x over previous
//
#include <hip/hip_runtime.h>
#include <math.h>

#define NN 100000
#define NE 500000
#define NREL 3
#define F 128
#define SCAN_BLK 1024
#define NBLK ((NN + SCAN_BLK - 1) / SCAN_BLK)   // 98 blocks per relation

__device__ __forceinline__ float sigm(float x) { return 1.f / (1.f + __expf(-x)); }

// ---- degree counting (int atomics) ----
__global__ void count_deg(const int* __restrict__ src, const int* __restrict__ dst,
                          int* __restrict__ cnt_out, int* __restrict__ cnt_in) {
  int i = blockIdx.x * blockDim.x + threadIdx.x;
  if (i >= NREL * NE) return;
  int r = i / NE;
  atomicAdd(&cnt_out[r * NN + src[i]], 1);
  atomicAdd(&cnt_in[r * NN + dst[i]], 1);
}

// counts -> rsqrt normalizers (separate src/dst buffers)
__global__ void make_rs(const int* __restrict__ cnt_out, const int* __restrict__ cnt_in,
                        float* __restrict__ rs_out, float* __restrict__ rs_in3) {
  int i = blockIdx.x * blockDim.x + threadIdx.x;
  if (i >= NREL * NN) return;
  int c0 = cnt_out[i];
  rs_out[i] = rsqrtf((float)(c0 < 1 ? 1 : c0));
  int c1 = cnt_in[i];
  rs_in3[i] = rsqrtf((float)(c1 < 1 ? 1 : c1)) * (1.f / 3.f);
}

// ---- two-level exclusive scan of cnt_in -> row_ptr ----
__global__ __launch_bounds__(256) void scan1(const int* __restrict__ cnt,
                                             int* __restrict__ excl, int* __restrict__ bsums) {
  int rb = blockIdx.x;                 // 0 .. NREL*NBLK-1
  int r = rb / NBLK, blk = rb % NBLK;
  int tid = (int)threadIdx.x;
  int v[4]; int sum = 0;
#pragma unroll
  for (int i = 0; i < 4; ++i) {
    int idx = blk * SCAN_BLK + tid * 4 + i;
    int c = (idx < NN) ? cnt[r * NN + idx] : 0;
    v[i] = sum; sum += c;
  }
  __shared__ int ts[256];
  ts[tid] = sum;
  __syncthreads();
  for (int off = 1; off < 256; off <<= 1) {
    int t = (tid >= off) ? ts[tid - off] : 0;
    __syncthreads();
    ts[tid] += t;
    __syncthreads();
  }
  int texcl = tid ? ts[tid - 1] : 0;
#pragma unroll
  for (int i = 0; i < 4; ++i) {
    int idx = blk * SCAN_BLK + tid * 4 + i;
    if (idx < NN) excl[r * NN + idx] = texcl + v[i];
  }
  if (tid == 255) bsums[rb] = ts[255];
}

__global__ __launch_bounds__(128) void scan2(int* __restrict__ bsums) {
  int r = blockIdx.x;
  int tid = (int)threadIdx.x;
  __shared__ int ts[128];
  ts[tid] = (tid < NBLK) ? bsums[r * NBLK + tid] : 0;
  __syncthreads();
  for (int off = 1; off < 128; off <<= 1) {
    int t = (tid >= off) ? ts[tid - off] : 0;
    __syncthreads();
    ts[tid] += t;
    __syncthreads();
  }
  if (tid < NBLK) bsums[r * NBLK + tid] = tid ? ts[tid - 1] : 0;
}

__global__ void scan3(int* __restrict__ row_ptr, const int* __restrict__ bsums,
                      int* __restrict__ cursor) {
  int i = blockIdx.x * blockDim.x + threadIdx.x;
  if (i >= NREL * NN) return;
  int r = i / NN, idx = i - r * NN, blk = idx / SCAN_BLK;
  int val = row_ptr[i] + bsums[r * NBLK + blk];
  row_ptr[i] = val;
  cursor[i] = val;
}

// counting-sort edges by dst; store src index at sorted position
__global__ void place_edges(const int* __restrict__ src, const int* __restrict__ dst,
                            int* __restrict__ cursor, int* __restrict__ sorted_src) {
  int i = blockIdx.x * blockDim.x + threadIdx.x;
  if (i >= NREL * NE) return;
  int r = i / NE;
  int pos = atomicAdd(&cursor[r * NN + dst[i]], 1);
  sorted_src[r * NE + pos] = src[i];
}

// h[n][:] = mean_r b[r][:]
__global__ void init_bias(float4* __restrict__ h4, const float4* __restrict__ b4) {
  int i = blockIdx.x * blockDim.x + threadIdx.x;
  if (i >= NN * (F / 4)) return;
  int q = i & 31;
  float4 a = b4[q], b = b4[32 + q], c = b4[64 + q];
  float4 v;
  v.x = (a.x + b.x + c.x) * (1.f / 3.f);
  v.y = (a.y + b.y + c.y) * (1.f / 3.f);
  v.z = (a.z + b.z + c.z) * (1.f / 3.f);
  v.w = (a.w + b.w + c.w) * (1.f / 3.f);
  h4[i] = v;
}

// Y = rowscale(opt-ReLU(A)) @ W ;  A:[NN,128] W:[128,128]
template <bool RELU>
__global__ __launch_bounds__(256, 4)
void gemm_rowscale(const float* __restrict__ A, const float* __restrict__ rs,
                   const float* __restrict__ W, float* __restrict__ Y) {
  __shared__ float As[128][34];
  __shared__ float Ws[32][132];
  const int row0 = blockIdx.x * 128;
  const int tid = (int)threadIdx.x;
  const int rg = tid >> 4;
  const int cg = tid & 15;
  float acc[8][8] = {};

  for (int kt = 0; kt < 4; ++kt) {
    __syncthreads();
#pragma unroll
    for (int it = 0; it < 4; ++it) {
      int lin = (it * 256 + tid) << 2;
      int r = lin >> 5, c = lin & 31;
      int gr = row0 + r;
      float4 v = make_float4(0.f, 0.f, 0.f, 0.f);
      if (gr < NN) {
        v = *(const float4*)(A + (size_t)gr * F + kt * 32 + c);
        float s = rs[gr];
        if (RELU) {
          v.x = fmaxf(v.x, 0.f) * s; v.y = fmaxf(v.y, 0.f) * s;
          v.z = fmaxf(v.z, 0.f) * s; v.w = fmaxf(v.w, 0.f) * s;
        } else {
          v.x *= s; v.y *= s; v.z *= s; v.w *= s;
        }
      }
      As[r][c] = v.x; As[r][c + 1] = v.y; As[r][c + 2] = v.z; As[r][c + 3] = v.w;
    }
#pragma unroll
    for (int it = 0; it < 4; ++it) {
      int lin = (it * 256 + tid) << 2;
      int kk = lin >> 7, j = lin & 127;
      float4 wv = *(const float4*)(W + (size_t)(kt * 32 + kk) * F + j);
      *(float4*)&Ws[kk][j] = wv;
    }
    __syncthreads();
#pragma unroll
    for (int kk = 0; kk < 32; ++kk) {
      float a[8];
#pragma unroll
      for (int i = 0; i < 8; ++i) a[i] = As[rg * 8 + i][kk];
      const float4 w0 = *(const float4*)&Ws[kk][cg * 4];
      const float4 w1 = *(const float4*)&Ws[kk][64 + cg * 4];
#pragma unroll
      for (int i = 0; i < 8; ++i) {
        acc[i][0] = fmaf(a[i], w0.x, acc[i][0]);
        acc[i][1] = fmaf(a[i], w0.y, acc[i][1]);
        acc[i][2] = fmaf(a[i], w0.z, acc[i][2]);
        acc[i][3] = fmaf(a[i], w0.w, acc[i][3]);
        acc[i][4] = fmaf(a[i], w1.x, acc[i][4]);
        acc[i][5] = fmaf(a[i], w1.y, acc[i][5]);
        acc[i][6] = fmaf(a[i], w1.z, acc[i][6]);
        acc[i][7] = fmaf(a[i], w1.w, acc[i][7]);
      }
    }
  }
#pragma unroll
  for (int i = 0; i < 8; ++i) {
    int gr = row0 + rg * 8 + i;
    if (gr < NN) {
      *(float4*)(Y + (size_t)gr * F + cg * 4) =
          make_float4(acc[i][0], acc[i][1], acc[i][2], acc[i][3]);
      *(float4*)(Y + (size_t)gr * F + 64 + cg * 4) =
          make_float4(acc[i][4], acc[i][5], acc[i][6], acc[i][7]);
    }
  }
}

// atomic-free CSR aggregation: one wave per dst node, lane = 2 feature cols.
// H[n] += rs_in3[n] * sum_{p in [beg,beg+cnt)} Y[sorted_src[p]]
__global__ __launch_bounds__(256) void aggregate(
    const float* __restrict__ Y, const int* __restrict__ sorted_src_r,
    const int* __restrict__ row_ptr_r, const int* __restrict__ cnt_r,
    const float* __restrict__ rs_in3_r, float* __restrict__ H) {
  int wid = (int)threadIdx.x >> 6, lane = (int)threadIdx.x & 63;
  int n = blockIdx.x * 4 + wid;
  if (n >= NN) return;
  int beg = row_ptr_r[n], cnt = cnt_r[n];
  const float2* yl = (const float2*)Y + lane;    // row stride = 64 float2
  float2 acc = make_float2(0.f, 0.f);
  int p = 0;
  for (; p + 4 <= cnt; p += 4) {
    int s0 = sorted_src_r[beg + p];
    int s1 = sorted_src_r[beg + p + 1];
    int s2 = sorted_src_r[beg + p + 2];
    int s3 = sorted_src_r[beg + p + 3];
    float2 v0 = yl[(size_t)s0 * 64];
    float2 v1 = yl[(size_t)s1 * 64];
    float2 v2 = yl[(size_t)s2 * 64];
    float2 v3 = yl[(size_t)s3 * 64];
    acc.x += (v0.x + v1.x) + (v2.x + v3.x);
    acc.y += (v0.y + v1.y) + (v2.y + v3.y);
  }
  for (; p < cnt; ++p) {
    int s = sorted_src_r[beg + p];
    float2 v = yl[(size_t)s * 64];
    acc.x += v.x; acc.y += v.y;
  }
  float sc = rs_in3_r[n];
  float2* hp = (float2*)(H + (size_t)n * F) + lane;
  float2 cur = *hp;
  cur.x += acc.x * sc;
  cur.y += acc.y * sc;
  *hp = cur;
}

// Fused BiLSTM single step (gates i,g,o only; f dead since c0=0, Whh dead).
__global__ __launch_bounds__(512, 4)
void lstm_fused(const float* __restrict__ H,
                const float* __restrict__ Wf, const float* __restrict__ bif,
                const float* __restrict__ bhf,
                const float* __restrict__ Wb, const float* __restrict__ bib,
                const float* __restrict__ bhb,
                float* __restrict__ out) {
  __shared__ float As[64][34];
  __shared__ float Ws[32][392];
  __shared__ float bsel[384];
  const int row0 = blockIdx.x * 64;
  const int tid = (int)threadIdx.x;
  const int rg = tid >> 5;
  const int cg = tid & 31;

  if (tid < 384) {
    int g = tid >> 7, j = tid & 127;
    int dir = j >> 6, jj = j & 63;
    int grow = (g == 0) ? jj : (g == 1) ? (128 + jj) : (192 + jj);
    bsel[tid] = dir ? (bib[grow] + bhb[grow]) : (bif[grow] + bhf[grow]);
  }

  float acc[3][4][4] = {};
  for (int kt = 0; kt < 4; ++kt) {
    __syncthreads();
    {
      int lin = tid << 2;
      int r = lin >> 5, c = lin & 31;
      int gr = row0 + r;
      float4 v = make_float4(0.f, 0.f, 0.f, 0.f);
      if (gr < NN) v = *(const float4*)(H + (size_t)gr * F + kt * 32 + c);
      As[r][c] = v.x; As[r][c + 1] = v.y; As[r][c + 2] = v.z; As[r][c + 3] = v.w;
    }
#pragma unroll
    for (int it = 0; it < 6; ++it) {
      int lin = it * 512 + tid;
      int m = lin % 384;
      int kq = lin / 384;
      int g = m >> 7, j = m & 127, dir = j >> 6, jj = j & 63;
      int grow = (g == 0) ? jj : (g == 1) ? (128 + jj) : (192 + jj);
      const float* Wd = dir ? Wb : Wf;
      float4 wv = *(const float4*)(Wd + (size_t)grow * F + kt * 32 + kq * 4);
      Ws[kq * 4 + 0][m] = wv.x;
      Ws[kq * 4 + 1][m] = wv.y;
      Ws[kq * 4 + 2][m] = wv.z;
      Ws[kq * 4 + 3][m] = wv.w;
    }
    __syncthreads();
#pragma unroll
    for (int kk = 0; kk < 32; ++kk) {
      float a[4];
#pragma unroll
      for (int i = 0; i < 4; ++i) a[i] = As[rg * 4 + i][kk];
      const float4 w0 = *(const float4*)&Ws[kk][cg * 4];
      const float4 w1 = *(const float4*)&Ws[kk][128 + cg * 4];
      const float4 w2 = *(const float4*)&Ws[kk][256 + cg * 4];
#pragma unroll
      for (int i = 0; i < 4; ++i) {
        acc[0][i][0] = fmaf(a[i], w0.x, acc[0][i][0]);
        acc[0][i][1] = fmaf(a[i], w0.y, acc[0][i][1]);
        acc[0][i][2] = fmaf(a[i], w0.z, acc[0][i][2]);
        acc[0][i][3] = fmaf(a[i], w0.w, acc[0][i][3]);
        acc[1][i][0] = fmaf(a[i], w1.x, acc[1][i][0]);
        acc[1][i][1] = fmaf(a[i], w1.y, acc[1][i][1]);
        acc[1][i][2] = fmaf(a[i], w1.z, acc[1][i][2]);
        acc[1][i][3] = fmaf(a[i], w1.w, acc[1][i][3]);
        acc[2][i][0] = fmaf(a[i], w2.x, acc[2][i][0]);
        acc[2][i][1] = fmaf(a[i], w2.y, acc[2][i][1]);
        acc[2][i][2] = fmaf(a[i], w2.z, acc[2][i][2]);
        acc[2][i][3] = fmaf(a[i], w2.w, acc[2][i][3]);
      }
    }
  }
#pragma unroll
  for (int i = 0; i < 4; ++i) {
    int gr = row0 + rg * 4 + i;
    if (gr < NN) {
      float4 o;
#pragma unroll
      for (int t = 0; t < 4; ++t) {
        int j = cg * 4 + t;
        float iv = acc[0][i][t] + bsel[j];
        float gv = acc[1][i][t] + bsel[128 + j];
        float ov = acc[2][i][t] + bsel[256 + j];
        float c = sigm(iv) * tanhf(gv);
        (&o.x)[t] = sigm(ov) * tanhf(c);
      }
      *(float4*)(out + (size_t)gr * F + cg * 4) = o;
    }
  }
}

extern "C" void kernel_launch(void* const* d_in, const int* in_sizes, int n_in,
                              void* d_out, int out_size, void* d_ws, size_t ws_size,
                              hipStream_t stream) {
  const float* x = (const float*)d_in[0];
  const int* src = (const int*)d_in[1];
  const int* dst = (const int*)d_in[2];
  const float* W1 = (const float*)d_in[3];
  const float* b1 = (const float*)d_in[4];
  const float* W2 = (const float*)d_in[5];
  const float* b2 = (const float*)d_in[6];
  const float* Wih_f = (const float*)d_in[7];
  const float* bih_f = (const float*)d_in[9];
  const float* bhh_f = (const float*)d_in[10];
  const float* Wih_b = (const float*)d_in[11];
  const float* bih_b = (const float*)d_in[13];
  const float* bhh_b = (const float*)d_in[14];
  float* out = (float*)d_out;

  // workspace carve-up
  float* rs_out = (float*)d_ws;                     // 3*NN f
  float* rs_in3 = rs_out + 3 * NN;                  // 3*NN f
  int* cnt_out = (int*)(rs_in3 + 3 * NN);           // 3*NN i
  int* cnt_in = cnt_out + 3 * NN;                   // 3*NN i
  int* row_ptr = cnt_in + 3 * NN;                   // 3*NN i
  int* cursor = row_ptr + 3 * NN;                   // 3*NN i
  int* bsums = cursor + 3 * NN;                     // NREL*NBLK (pad 1024)
  int* sorted_src = bsums + 1024;                   // 3*NE i
  float* y = (float*)(sorted_src + 3 * NE);         // NN*F f
  float* h1 = y + (size_t)NN * F;                   // NN*F f

  // degrees + CSR build (shared by both layers)
  hipMemsetAsync(cnt_out, 0, (size_t)6 * NN * sizeof(int), stream);
  count_deg<<<(NREL * NE + 255) / 256, 256, 0, stream>>>(src, dst, cnt_out, cnt_in);
  make_rs<<<(NREL * NN + 255) / 256, 256, 0, stream>>>(cnt_out, cnt_in, rs_out, rs_in3);
  scan1<<<NREL * NBLK, 256, 0, stream>>>(cnt_in, row_ptr, bsums);
  scan2<<<NREL, 128, 0, stream>>>(bsums);
  scan3<<<(NREL * NN + 255) / 256, 256, 0, stream>>>(row_ptr, bsums, cursor);
  place_edges<<<(NREL * NE + 255) / 256, 256, 0, stream>>>(src, dst, cursor, sorted_src);

  // layer 1
  init_bias<<<(NN * 32 + 255) / 256, 256, 0, stream>>>((float4*)h1, (const float4*)b1);
  for (int r = 0; r < NREL; ++r) {
    gemm_rowscale<false><<<(NN + 127) / 128, 256, 0, stream>>>(
        x, rs_out + r * NN, W1 + (size_t)r * F * F, y);
    aggregate<<<(NN + 3) / 4, 256, 0, stream>>>(
        y, sorted_src + (size_t)r * NE, row_ptr + r * NN, cnt_in + r * NN,
        rs_in3 + r * NN, h1);
  }

  // layer 2
  init_bias<<<(NN * 32 + 255) / 256, 256, 0, stream>>>((float4*)out, (const float4*)b2);
  for (int r = 0; r < NREL; ++r) {
    gemm_rowscale<true><<<(NN + 127) / 128, 256, 0, stream>>>(
        h1, rs_out + r * NN, W2 + (size_t)r * F * F, y);
    aggregate<<<(NN + 3) / 4, 256, 0, stream>>>(
        y, sorted_src + (size_t)r * NE, row_ptr + r * NN, cnt_in + r * NN,
        rs_in3 + r * NN, out);
  }

  // fused BiLSTM step, in place on d_out
  lstm_fused<<<(NN + 63) / 64, 512, 0, stream>>>(out, Wih_f, bih_f, bhh_f,
                                                 Wih_b, bih_b, bhh_b, out);
}